// Round 7
// baseline (116.533 us; speedup 1.0000x reference)
//
#include <hip/hip_runtime.h>

#define B_    16
#define CIN_  128
#define COUT_ 128
#define N_    4096
#define K_    16

typedef __attribute__((ext_vector_type(8))) _Float16 f16x8;   // 8 f16 = 4 VGPR
typedef __attribute__((ext_vector_type(2))) _Float16 f16x2;   // arithmetic type
typedef __attribute__((ext_vector_type(2))) __fp16   h16x2;   // pkrtz ret type
typedef __attribute__((ext_vector_type(4))) float f32x4;
typedef __attribute__((ext_vector_type(4))) int   i32x4;

// v_cvt_pkrtz_f16_f32 returns __fp16x2; bitcast to the _Float16x2 we compute in
__device__ inline f16x2 pkrtz(float a, float b) {
  union { h16x2 r; f16x2 f; } u;
  u.r = __builtin_amdgcn_cvt_pkrtz(a, b);
  return u.f;
}
__device__ inline unsigned h2u(f16x2 h) {          // bitcast half2 -> u32
  union { f16x2 h; unsigned u; } x; x.h = h; return x.u;
}
__device__ inline f16x2 u2h(unsigned u) {          // bitcast u32 -> half2
  union { unsigned u; f16x2 h; } x; x.u = u; return x.h;
}
__device__ inline unsigned packh(float a, float b) {  // 2x v_cvt_f16_f32 (RNE) + pack
  f16x2 p; p[0] = (_Float16)a; p[1] = (_Float16)b; return h2u(p);
}

// ---------------------------------------------------------------------------
// R7. R6 falsified VALU-boundedness (4x fewer conv/unpack ops -> 0 delta).
// Two structural fixes, one per kernel:
// (1) gemm: SWAP MFMA operands -> D rows=co (reg dim), cols=n (lane dim);
//     each lane holds 4 consecutive co at fixed n -> pack f16, store 8B
//     directly from registers. Deletes the He transpose (73.7KB LDS), its
//     barrier, and its 8-way-conflicted 32 ds_writes/thread (the measured
//     950K SQ_LDS_BANK_CONFLICT: He row stride 72 dw ≡ 8 banks, quad
//     distance 4 rows ≡ 0 mod 32 -> all quads on the same 8 banks).
// (2) aggr: in-flight-bytes starved (needs ~27KB/CU to sustain L2 BW, had
//     ~2KB). Grid 2048 (32n x 128co), launch_bounds(256,8) -> 8 blocks/CU
//     = 32 waves/CU, + explicit depth-2 gather pipeline (static buffers).
//
// XCD-affinity (proven): round-robin dispatch pins batch-pair b>>1 = l&7 in
// BOTH kernels -> aggr gathers hit the L2 that gemm filled.
// ---------------------------------------------------------------------------
// Kernel 1: h[b][n][co] = f16(relu(sum_ci W[co][ci]*x[b][ci][n]))
// 256 blocks x 1024 thr; tile 256n x 128co; LDS = Wl only (34.8 KB).
// ---------------------------------------------------------------------------
__global__ __launch_bounds__(1024, 4) void gemm_relu_k(
    const float* __restrict__ W, const float* __restrict__ x,
    unsigned short* __restrict__ h) {
  __shared__ unsigned short Wl[128 * 136];   // [co][ci] f16, +8 pad (34.8 KB)
  const int tid  = threadIdx.x;
  const int l    = blockIdx.x;          // 0..255
  const int slot = l >> 3;              // 0..31
  const int b    = ((l & 7) << 1) | (slot >> 4);
  const int n0   = (slot & 15) * 256;

  // ---- stage W fp32 -> f16 -> LDS: 4x v_cvt_pkrtz per 8 floats ----
#pragma unroll
  for (int r = 0; r < 2; ++r) {
    int id  = tid + 1024 * r;   // 0..2047 segments of 8 floats
    int co  = id >> 4;          // 0..127
    int seg = id & 15;          // 8-elt segment along ci
    const float4* wp = reinterpret_cast<const float4*>(W + co * CIN_ + 8 * seg);
    float4 v0 = wp[0];
    float4 v1 = wp[1];
    f16x2 q0 = pkrtz(v0.x, v0.y);
    f16x2 q1 = pkrtz(v0.z, v0.w);
    f16x2 q2 = pkrtz(v1.x, v1.y);
    f16x2 q3 = pkrtz(v1.z, v1.w);
    *reinterpret_cast<uint4*>(&Wl[co * 136 + 8 * seg]) =
        make_uint4(h2u(q0), h2u(q1), h2u(q2), h2u(q3));
  }

  const int lane = tid & 63;
  const int w    = tid >> 6;    // wave 0..15 -> n slice [n0+16w, +16)
  const int m    = lane & 15;
  const int quad = lane >> 4;

  // ---- x-fragments straight from global (overlap the W staging above) ----
  const float* xb = x + (size_t)b * CIN_ * N_ + n0 + 16 * w + m;
  f16x8 a[4];
#pragma unroll
  for (int s = 0; s < 4; ++s)
#pragma unroll
    for (int jj = 0; jj < 4; ++jj) {
      float e0 = xb[(size_t)(32 * s + 8 * quad + 2 * jj)     * N_];
      float e1 = xb[(size_t)(32 * s + 8 * quad + 2 * jj + 1) * N_];
      f16x2 p = pkrtz(e0, e1);
      a[s][2 * jj]     = p[0];
      a[s][2 * jj + 1] = p[1];
    }

  __syncthreads();

  // ---- MFMA with SWAPPED operands: D rows = co (4quad+r), cols = n (m).
  //      Lane holds co = 16t+4quad+{0..3} at n = n0+16w+m -> 8B packed store.
  unsigned short* hrow = h + ((size_t)b * N_ + n0 + 16 * w + m) * COUT_;
#pragma unroll
  for (int t = 0; t < 8; ++t) {   // 8 co-tiles of 16
    f32x4 c = {0.f, 0.f, 0.f, 0.f};
#pragma unroll
    for (int s = 0; s < 4; ++s) { // K = 4 x 32
      f16x8 wf = *reinterpret_cast<const f16x8*>(
          &Wl[(16 * t + m) * 136 + 32 * s + 8 * quad]);
      c = __builtin_amdgcn_mfma_f32_16x16x32_f16(wf, a[s], c, 0, 0, 0);
    }
    float r0 = c[0] > 0.f ? c[0] : 0.f;   // ReLU
    float r1 = c[1] > 0.f ? c[1] : 0.f;
    float r2 = c[2] > 0.f ? c[2] : 0.f;
    float r3 = c[3] > 0.f ? c[3] : 0.f;
    // co = 16t + 4quad + {0,1,2,3}: 4 consecutive f16 = 8 B, 8-aligned
    *reinterpret_cast<uint2*>(hrow + 16 * t + 4 * quad) =
        make_uint2(packh(r0, r1), packh(r2, r3));
  }
}

// ---------------------------------------------------------------------------
// Kernel 2: out[b][co][n] = (sum_{17} h[b][idx'][:])/17 + bias, idx' incl self
// 2048 blocks x 256 thr; tile 32n x 128co; 8 blocks/CU (launch_bounds(256,8),
// LDS 2.2KB); q=tid&15 -> 8 co (16 lanes = one 256B h row), g=tid>>4 -> 2 n;
// explicit depth-2 software pipeline over k (static va/vb buffers).
// ---------------------------------------------------------------------------
__global__ __launch_bounds__(256, 8) void aggr_k(
    const unsigned short* __restrict__ h, const int* __restrict__ ei,
    const float* __restrict__ bias, float* __restrict__ out) {
  __shared__ int idx_t[17 * 32];  // [k][n], k=16 is the self loop
  const int tid  = threadIdx.x;
  const int l    = blockIdx.x;                    // 0..2047
  const int rest = l >> 3;                        // 0..255
  const int b    = ((l & 7) << 1) | (rest >> 7);
  const int n0   = (rest & 127) * 32;

  {  // stage+transpose neighbor indices (coalesced int4, NT to spare L2)
    if (tid < 128) {
      int n  = tid >> 2;       // 0..31
      int kq = tid & 3;        // int4 along k
      i32x4 v = __builtin_nontemporal_load(
          reinterpret_cast<const i32x4*>(ei + ((size_t)b * N_ + n0 + n) * K_) + kq);
      idx_t[(4 * kq + 0) * 32 + n] = v.x;
      idx_t[(4 * kq + 1) * 32 + n] = v.y;
      idx_t[(4 * kq + 2) * 32 + n] = v.z;
      idx_t[(4 * kq + 3) * 32 + n] = v.w;
    }
    if (tid < 32) idx_t[16 * 32 + tid] = n0 + tid;  // self loop
  }
  __syncthreads();

  const int q = tid & 15;   // co = 8q..8q+7
  const int g = tid >> 4;   // n_local = 2g, 2g+1
  const unsigned short* hb = h + (size_t)b * N_ * COUT_;

  // packed f16 accumulators [n_local][dword of co-pair]; f16 safe: terms
  // non-negative, sums <~20, ulp(20)=0.016 -> ~0.002 err after /17.
  f16x2 acc2[2][4];
#pragma unroll
  for (int jj = 0; jj < 2; ++jj)
#pragma unroll
    for (int d = 0; d < 4; ++d) acc2[jj][d] = (f16x2)(_Float16)0;

#define LDK(K, V)                                                          \
  {                                                                        \
    int na_ = idx_t[(K) * 32 + 2 * g];                                     \
    int nb_ = idx_t[(K) * 32 + 2 * g + 1];                                 \
    V[0] = *reinterpret_cast<const uint4*>(hb + (size_t)na_ * COUT_ + 8 * q); \
    V[1] = *reinterpret_cast<const uint4*>(hb + (size_t)nb_ * COUT_ + 8 * q); \
  }
#define ACCK(V)                                                            \
  {                                                                        \
    _Pragma("unroll")                                                      \
    for (int jj = 0; jj < 2; ++jj) {                                       \
      acc2[jj][0] += u2h(V[jj].x);                                         \
      acc2[jj][1] += u2h(V[jj].y);                                         \
      acc2[jj][2] += u2h(V[jj].z);                                         \
      acc2[jj][3] += u2h(V[jj].w);                                         \
    }                                                                      \
  }

  uint4 va[2], vb[2];
  LDK(0, va);
#pragma unroll
  for (int k = 0; k < 17; k += 2) {   // depth-2 pipeline, all-static indexing
    if (k + 1 < 17) LDK(k + 1, vb);
    ACCK(va);
    if (k + 2 < 17) LDK(k + 2, va);
    if (k + 1 < 17) ACCK(vb);
  }
#undef LDK
#undef ACCK

  const float norm = 1.0f / 17.0f;
  const float4 bv0 = *reinterpret_cast<const float4*>(bias + 8 * q);
  const float4 bv1 = *reinterpret_cast<const float4*>(bias + 8 * q + 4);
  float* ob = out + (size_t)b * COUT_ * N_ + n0 + 2 * g;
#pragma unroll
  for (int c = 0; c < 8; ++c) {
    int co = 8 * q + c;
    float bb = (c < 4) ? ((c == 0) ? bv0.x : (c == 1) ? bv0.y : (c == 2) ? bv0.z : bv0.w)
                       : ((c == 4) ? bv1.x : (c == 5) ? bv1.y : (c == 6) ? bv1.z : bv1.w);
    float2 r;
    r.x = (float)acc2[0][c >> 1][c & 1] * norm + bb;
    r.y = (float)acc2[1][c >> 1][c & 1] * norm + bb;
    *reinterpret_cast<float2*>(ob + (size_t)co * N_) = r;  // 8B stores
  }
}

extern "C" void kernel_launch(void* const* d_in, const int* in_sizes, int n_in,
                              void* d_out, int out_size, void* d_ws, size_t ws_size,
                              hipStream_t stream) {
  const float* x    = (const float*)d_in[0];
  const int*   ei   = (const int*)d_in[1];   // [2][B][N][K]; plane 0
  const float* W    = (const float*)d_in[2];
  const float* bias = (const float*)d_in[3];
  float* out = (float*)d_out;
  unsigned short* h = (unsigned short*)d_ws;  // 16 MB (f16)

  gemm_relu_k<<<dim3(256), dim3(1024), 0, stream>>>(W, x, h);
  aggr_k<<<dim3(2048), dim3(256), 0, stream>>>(h, ei, bias, out);
}